// Round 8
// baseline (179.578 us; speedup 1.0000x reference)
//
#include <hip/hip_runtime.h>
#include <math.h>
#include <stdint.h>

// B,H,W,C = 4,384,384,48; KERNEL=3 -> 128x128 output, 48 "channels" g.
// Output F=((b*128+r)*128+cc)*48+g consumes 9 contiguous floats at input row
// (b*384+3r+kr), float offset cc*144+(g&15)*9, kr=g>>4.
// Structure = R5 (best measured). Single change: v_exp_f32 (measured ~46 cyc
// SIMD-blocking occupancy via R1/R5 back-solve) -> 12-instr VALU poly exp2.
#define ROW_STRIDE 18432
#define EPS 1e-4f

static __device__ __forceinline__ float rcp_f(float a) {
    return __builtin_amdgcn_rcpf(a);      // v_rcp_f32, 1 ulp
}

// exp2(x) for x <= 0, branchless, ~2 ulp (Cephes deg-6 on [-0.5,0.5]).
// Clamp at -126: true exp2 < 1.18e-38 there; error is absolute < 1.2e-38 and
// cannot flip any comparison (ms*0.2 >= 0.2 always via the exact +1.0 slot).
static __device__ __forceinline__ float exp2_poly(float x) {
    x = fmaxf(x, -126.0f);
    const float n = __builtin_rintf(x);            // v_rndne_f32
    const float f = x - n;                          // exact, in [-0.5, 0.5]
    float p = 1.535336188319500e-4f;
    p = fmaf(p, f, 1.339887440266574e-3f);
    p = fmaf(p, f, 9.618437357674640e-3f);
    p = fmaf(p, f, 5.550332471162809e-2f);
    p = fmaf(p, f, 2.402264791363012e-1f);
    p = fmaf(p, f, 6.931472028550421e-1f);
    const float r = fmaf(f, p, 1.0f);               // 2^f
    const int ni = (int)n;                          // exact int in [-126, 0]
    const float s = __builtin_bit_cast(float, (ni << 23) + 0x3F800000); // 2^n
    return r * s;
}

__global__ __launch_bounds__(256) void fuzzy_pool_kernel(
        const float* __restrict__ x, float* __restrict__ out) {
    __shared__ float s[2304];             // 9216 B staged input

    const int tid = threadIdx.x;
    const int bid = blockIdx.x;           // ((b*128+r)*3 + kr)*8 + c8
    const int c8 = bid & 7;
    const int t1 = bid >> 3;
    const int kr = t1 % 3;                // scalar magic-mul
    const int t2 = t1 / 3;
    const int r  = t2 & 127;
    const int b  = t2 >> 7;

    const float* __restrict__ src =
        x + ((size_t)(b * 384 + 3 * r + kr) * ROW_STRIDE + c8 * 2304);

    // ---- coalesced global -> LDS staging: 576 float4, 16B/lane ----
    const float4* __restrict__ s4 = (const float4*)src;
    float4* l4 = (float4*)s;
    l4[tid]       = s4[tid];
    l4[tid + 256] = s4[tid + 256];
    if (tid < 64) l4[tid + 512] = s4[tid + 512];
    __syncthreads();

    // thread (i = cc offset 0..15, j = g' 0..15)
    const int i = tid >> 4;
    const int j = tid & 15;
    const float* __restrict__ vp = s + (i * 144 + j * 9);  // 2-way banks: free

    float v[9];
#pragma unroll
    for (int t = 0; t < 9; ++t) v[t] = vp[t];

    const float R3 = 1.0f/3.0f, R5 = 0.2f, R7 = 1.0f/7.0f, R9 = 1.0f/9.0f;
    const float NC = -0.5f * 1.44269504088896340736f;   // -0.5*log2(e)

    // ---- membership(x): nested sums ----
    const float s3 = v[3] + v[4] + v[5];
    const float s5 = s3 + v[2] + v[6];
    const float s7 = s5 + v[1] + v[7];
    const float s9 = s7 + v[0] + v[8];
    const float m3 = s3 * R3, m5 = s5 * R5, m7 = s7 * R7, m9 = s9 * R9;

    float kmm[5];
    kmm[0] = m7; kmm[1] = m5; kmm[2] = m3; kmm[3] = v[4]; kmm[4] = m9;

    const float v_avg = (m7 + m5 + m3 + v[4] + m9) * R5;

    // ---- omega = |x - v_avg|; var = membership(omega) + eps ----
    float w[9];
#pragma unroll
    for (int t = 0; t < 9; ++t) w[t] = fabsf(v[t] - v_avg);

    const float t3 = w[3] + w[4] + w[5];
    const float t5 = t3 + w[2] + w[6];
    const float t7 = t5 + w[1] + w[7];
    const float t9 = t7 + w[0] + w[8];
    const float var4 = t9 * R9 + EPS;        // var[...,4] (m_only_var probe)

    float c[5];                               // c_j = -0.5*log2e / var_j
    c[0] = NC * rcp_f(t7 * R7 + EPS);
    c[1] = NC * rcp_f(t5 * R5 + EPS);
    c[2] = NC * rcp_f(t3 * R3 + EPS);
    c[3] = NC * rcp_f(w[4] + EPS);
    c[4] = NC * rcp_f(var4);

    // ---- pi[jj][t] = 2^(c_jj * d^2); sum over jj all t, max over jj t!=4 ----
    // Exact: pi[3][4] = 1.0 bit-exactly; all pi <= 1 so max_pi[4] = 1.0 and
    // t=4 drops out of the thresh min-tree.
    float sum_pi[9], max_pi[9];
#pragma unroll
    for (int t = 0; t < 9; ++t) { sum_pi[t] = 0.f; max_pi[t] = 0.f; }

#pragma unroll
    for (int jj = 0; jj < 5; ++jj) {
        const float k  = kmm[jj];
        const float cj = c[jj];
#pragma unroll
        for (int t = 0; t < 9; ++t) {
            if (jj == 3 && t == 4) {          // d = v[4]-v[4] = +-0 exactly
                sum_pi[4] += 1.0f;            // same summation slot/order
                continue;
            }
            const float d  = v[t] - k;
            const float pi = exp2_poly(cj * d * d);   // VALU, no trans pipe
            sum_pi[t] += pi;
            if (t != 4) max_pi[t] = fmaxf(max_pi[t], pi);
        }
    }

    float thresh = fminf(fminf(max_pi[0], max_pi[1]), max_pi[2]);
    thresh = fminf(thresh, max_pi[3]);
    thresh = fminf(fminf(thresh, max_pi[5]), max_pi[6]);
    thresh = fminf(fminf(thresh, max_pi[7]), max_pi[8]);

    // any_t(sum_pi[t]*0.2 > thresh)  <=>  max_t(sum_pi)*0.2 > thresh
    float ms = fmaxf(fmaxf(sum_pi[0], sum_pi[1]), sum_pi[2]);
    ms = fmaxf(fmaxf(ms, sum_pi[3]), sum_pi[4]);
    ms = fmaxf(fmaxf(ms, sum_pi[5]), sum_pi[6]);
    ms = fmaxf(fmaxf(ms, sum_pi[7]), sum_pi[8]);
    const bool m_mem = (ms * R5) > thresh;

    // weighted-average denoising; the 0.2 factor cancels in the ratio
    float sn = 0.f, sd = 0.f;
#pragma unroll
    for (int t = 0; t < 9; ++t) { sn += sum_pi[t] * v[t]; sd += sum_pi[t]; }
    const float denoised = sn * rcp_f(sd);

    const float res = m_mem ? m9 : ((var4 < EPS) ? v_avg : denoised);

    const int cc = c8 * 16 + i;
    const int g  = kr * 16 + j;
    out[((size_t)((b * 128 + r) * 128 + cc)) * 48 + g] = res;
}

extern "C" void kernel_launch(void* const* d_in, const int* in_sizes, int n_in,
                              void* d_out, int out_size, void* d_ws, size_t ws_size,
                              hipStream_t stream) {
    (void)in_sizes; (void)n_in; (void)d_ws; (void)ws_size; (void)out_size;
    const float* x = (const float*)d_in[0];
    float* out = (float*)d_out;
    const int blocks = 4 * 128 * 3 * 8;   // (b, r, kr, c8) = 12288
    fuzzy_pool_kernel<<<blocks, 256, 0, stream>>>(x, out);
}